// Round 9
// baseline (1761.511 us; speedup 1.0000x reference)
//
#include <hip/hip_runtime.h>
#include <hip/hip_bf16.h>
#include <math.h>

typedef __attribute__((ext_vector_type(8))) short short8;
typedef __attribute__((ext_vector_type(4))) float f32x4;
typedef unsigned short u16;
typedef unsigned int u32;

__device__ __forceinline__ u16 f2bf(float f) {
  union { float f; u32 u; } x; x.f = f;
  return (u16)((x.u + 0x7fffu + ((x.u >> 16) & 1u)) >> 16);
}
__device__ __forceinline__ float sigm(float v) {
  return __builtin_amdgcn_rcpf(1.0f + __expf(-v));
}
__device__ __forceinline__ float tanh_fast(float v) {
  return 1.0f - 2.0f * __builtin_amdgcn_rcpf(1.0f + __expf(2.0f * v));
}

#define MFMA __builtin_amdgcn_mfma_f32_16x16x32_bf16
#define XS  (512*576)   // one x copy (u16 elems)
#define HSL (512*512)   // one h ring slot (u16 elems)

// PROVEN: 16 x 16B loads (64B stride = one K-slice of a 512-col bf16 row).
#define LDG16_BODY(FL)                                        \
    "global_load_dwordx4 %0, %16, off " FL "\n\t"             \
    "global_load_dwordx4 %1, %16, off offset:64 " FL "\n\t"   \
    "global_load_dwordx4 %2, %16, off offset:128 " FL "\n\t"  \
    "global_load_dwordx4 %3, %16, off offset:192 " FL "\n\t"  \
    "global_load_dwordx4 %4, %16, off offset:256 " FL "\n\t"  \
    "global_load_dwordx4 %5, %16, off offset:320 " FL "\n\t"  \
    "global_load_dwordx4 %6, %16, off offset:384 " FL "\n\t"  \
    "global_load_dwordx4 %7, %16, off offset:448 " FL "\n\t"  \
    "global_load_dwordx4 %8, %16, off offset:512 " FL "\n\t"  \
    "global_load_dwordx4 %9, %16, off offset:576 " FL "\n\t"  \
    "global_load_dwordx4 %10, %16, off offset:640 " FL "\n\t" \
    "global_load_dwordx4 %11, %16, off offset:704 " FL "\n\t" \
    "global_load_dwordx4 %12, %16, off offset:768 " FL "\n\t" \
    "global_load_dwordx4 %13, %16, off offset:832 " FL "\n\t" \
    "global_load_dwordx4 %14, %16, off offset:896 " FL "\n\t" \
    "global_load_dwordx4 %15, %16, off offset:960 " FL
#define LDG16_OPS(a, base)                                                     \
    : "=&v"(a[0]), "=&v"(a[1]), "=&v"(a[2]), "=&v"(a[3]), "=&v"(a[4]),         \
      "=&v"(a[5]), "=&v"(a[6]), "=&v"(a[7]), "=&v"(a[8]), "=&v"(a[9]),         \
      "=&v"(a[10]), "=&v"(a[11]), "=&v"(a[12]), "=&v"(a[13]), "=&v"(a[14]),    \
      "=&v"(a[15])                                                             \
    : "v"(base) : "memory"

__device__ __forceinline__ void ldg16nw_sc0(short8 a[16], const u16* base) {
  asm volatile(LDG16_BODY("sc0") LDG16_OPS(a, base));    // local-L2 fresh
}

// Counted waits + sched_barrier (rule #18). Used ONLY in asm-only windows.
#define VMCNT(N) do { asm volatile("s_waitcnt vmcnt(" #N ")" ::: "memory"); \
                      __builtin_amdgcn_sched_barrier(0); } while (0)

// PROVEN (R0) rendezvous: poll two agent-scope atomic counters, then barrier.
__device__ __forceinline__ void waits_nf(unsigned* a, unsigned ta, unsigned* b, unsigned tb) {
  if (threadIdx.x == 0) {
    while (__hip_atomic_load(a, __ATOMIC_RELAXED, __HIP_MEMORY_SCOPE_AGENT) < ta)
      __builtin_amdgcn_s_sleep(1);
    while (__hip_atomic_load(b, __ATOMIC_RELAXED, __HIP_MEMORY_SCOPE_AGENT) < tb)
      __builtin_amdgcn_s_sleep(1);
  }
  __syncthreads();
}

// PROVEN (R5) per-lane 128-col dot vs LDS-resident W_fc.
__device__ __forceinline__ float ydot(const short8 a[16], const float* wfcl, int quad) {
  float y = 0.0f;
  #pragma unroll
  for (int s = 0; s < 16; ++s) {
    const float4 wa = *(const float4*)&wfcl[32 * s + quad * 8];
    const float4 wb = *(const float4*)&wfcl[32 * s + quad * 8 + 4];
    union { short8 v; u32 u4[4]; } aa; aa.v = a[s];
    #pragma unroll
    for (int k = 0; k < 4; ++k) {
      union { u32 u; float f; } lo, hi;
      lo.u = aa.u4[k] << 16;
      hi.u = aa.u4[k] & 0xffff0000u;
      float w0 = (k < 2) ? ((k & 1) ? wa.z : wa.x) : ((k & 1) ? wb.z : wb.x);
      float w1 = (k < 2) ? ((k & 1) ? wa.w : wa.y) : ((k & 1) ? wb.w : wb.y);
      y = fmaf(lo.f, w0, y);
      y = fmaf(hi.f, w1, y);
    }
  }
  return y;
}

// 16 K-slices x 3 gates from LDS (base block B0; gate stride 16 blocks).
#define MFMA3X16_LDS(A, B0, A0, A1, A2) do {                          \
    _Pragma("unroll")                                                 \
    for (int s_ = 0; s_ < 16; ++s_) {                                 \
      A0 = MFMA((A)[s_], wlds[((B0)+s_)*64+lane],    A0, 0, 0, 0);    \
      A1 = MFMA((A)[s_], wlds[((B0)+16+s_)*64+lane], A1, 0, 0, 0);    \
      A2 = MFMA((A)[s_], wlds[((B0)+32+s_)*64+lane], A2, 0, 0, 0); } } while (0)

// FUSED persistent 2-layer GRU — XCD-local steady state, zero MALL data.
// Identical to R8 (which RAN but failed numerics) except the weight-pack
// index fix: R8 computed `b = blk & 47` intending mod-48 — 47=0b101111
// clears bit 4, so z-gate blocks 16..31 aliased onto r-gate 0..15 and the
// second matrix's blocks scrambled. Fixed with explicit subtraction.
// Topology recap: 256 WGs = 8 groups (g = bid&7, same XCD class) x 32
// col-blocks. Group g owns rows 64g..64g+63 of BOTH layers; phase1 = layer1,
// phase2 = layer2. Rings: plain stores -> local-L2 dirty; sc0 asm reads.
// Sync: R0-proven agent-atomic counters cA/cB per group.
//  phase2(u) waits cA>=32(u+1), cB>=32u; phase1(u)'s needs are implied by
//  phase2(u-1)'s waits => phase1 never polls; 2-slot rings safe.
// LDS 96KB: Whh1 (0..47) + Wih2 (48..95). Wih1 + Whh2 stream via nt loads
// from per-col-block L2-resident packs. Workspace 6.43MB (< proven 7.13MB).
__global__ __launch_bounds__(256, 1) void gru_fused(
    const float* __restrict__ xin, const float* __restrict__ h1in, const float* __restrict__ h2in,
    const float* __restrict__ Wih1, const float* __restrict__ Whh1,
    const float* __restrict__ bih1, const float* __restrict__ bhh1,
    const float* __restrict__ Wih2, const float* __restrict__ Whh2,
    const float* __restrict__ bih2, const float* __restrict__ bhh2,
    const float* __restrict__ Wfc, const float* __restrict__ bfc,
    float* __restrict__ out, u16* __restrict__ wsb, unsigned* __restrict__ barc)
{
  const int bid  = blockIdx.x;
  const int g    = bid & 7;
  const int wgi  = bid >> 3;
  const int n0   = wgi * 16;
  const int tid  = threadIdx.x;
  const int w    = tid >> 6;
  const int lane = tid & 63;
  const int quad = lane >> 4;
  const int m16  = lane & 15;
  const int R0   = g * 64;
  const int xrow = R0 + w * 16 + m16;
  const int nn   = n0 + m16;

  u16* x0  = wsb;                     // [512][576] bf16
  u16* x1  = x0 + XS;                 // shifted copy (odd steps)
  u16* h1r = x1 + XS;                 // 2-slot ring
  u16* h2r = h1r + 2 * HSL;           // 2-slot ring
  short8* wfx  = (short8*)(h2r + 2 * HSL);              // packs
  short8* wfm1 = wfx + (size_t)wgi * 96 * 64;           // Wih1 blk 0..47
  short8* wfm2 = wfm1 + 48 * 64;                        // Whh2 blk 0..47

  __shared__ short8 wlds[96 * 64];    // Whh1 (0..47), Wih2 (48..95)
  __shared__ float wfcl[512];

  unsigned* cA = barc + g * 32;            // layer-1 step counter (group g)
  unsigned* cB = barc + 256 + g * 32;      // layer-2 step counter
  unsigned* cinit = barc + 512;

  // ---------------- one-time init (group-local writes) ----------------
  for (int i = wgi * 256 + tid; i < 64 * 575; i += 32 * 256) {
    int r = i / 575, c = i - r * 575;
    int row = R0 + r;
    u16 bv = f2bf(xin[row * 575 + c]);
    x0[row * 576 + c] = bv;
    if (c >= 1) x1[row * 576 + (c - 1)] = bv;
  }
  for (int i = tid; i < 64 * 16; i += 256) {      // ring slot 1 = h(-1)
    int r = i >> 4, cL = i & 15;
    int row = R0 + r, col = n0 + cL;
    h1r[HSL + row * 512 + col] = f2bf(h1in[row * 512 + col]);
    h2r[HSL + row * 512 + col] = f2bf(h2in[row * 512 + col]);
  }
  // packs: Wih1 (blk<48), Whh2 (blk>=48); per-wgi content, written
  // identically by all 8 groups (benign) -> L2-dirty copy on every XCD.
  for (int i = tid; i < 96 * 64; i += 256) {
    int blk = i >> 6, l = i & 63;
    int b = (blk < 48) ? blk : blk - 48;           // FIXED (was blk & 47)
    const float* M = blk < 48 ? Wih1 : Whh2;
    int t = b >> 4, s = b & 15;
    int gr = t * 512 + n0 + (l & 15);
    int k0 = s * 32 + (l >> 4) * 8;
    short8 pk;
    #pragma unroll
    for (int j = 0; j < 8; ++j) pk[j] = (short)f2bf(M[gr * 512 + k0 + j]);
    wfm1[blk * 64 + l] = pk;
  }
  // LDS: Whh1 (0..47), Wih2 (48..95)
  for (int i = tid; i < 96 * 64; i += 256) {
    int blk = i >> 6, l = i & 63;
    int b = (blk < 48) ? blk : blk - 48;           // FIXED (was blk & 47)
    const float* M = blk < 48 ? Whh1 : Wih2;
    int t = b >> 4, s = b & 15;
    int gr = t * 512 + n0 + (l & 15);
    int k0 = s * 32 + (l >> 4) * 8;
    short8 pk;
    #pragma unroll
    for (int j = 0; j < 8; ++j) pk[j] = (short)f2bf(M[gr * 512 + k0 + j]);
    wlds[blk * 64 + l] = pk;
  }
  for (int i = tid; i < 512; i += 256) wfcl[i] = Wfc[i];

  float hreg1[4], hreg2[4];
  #pragma unroll
  for (int q = 0; q < 4; ++q) {
    int row = R0 + w * 16 + quad * 4 + q;
    hreg1[q] = h1in[row * 512 + nn];
    hreg2[q] = h2in[row * 512 + nn];
  }

  const float b1r = bih1[nn] + bhh1[nn];
  const float b1z = bih1[512 + nn] + bhh1[512 + nn];
  const float b1i = bih1[1024 + nn];
  const float b1h = bhh1[1024 + nn];
  const float b2r = bih2[nn] + bhh2[nn];
  const float b2z = bih2[512 + nn] + bhh2[512 + nn];
  const float b2i = bih2[1024 + nn];
  const float b2h = bhh2[1024 + nn];
  const float bfcv = bfc[0];

  // PROVEN global init barrier: release (wb) + acquire (inv), one-time.
  __syncthreads();
  if (tid == 0) {
    __builtin_amdgcn_fence(__ATOMIC_RELEASE, "agent");
    __hip_atomic_fetch_add(cinit, 1u, __ATOMIC_RELAXED, __HIP_MEMORY_SCOPE_AGENT);
    while (__hip_atomic_load(cinit, __ATOMIC_RELAXED, __HIP_MEMORY_SCOPE_AGENT) < 256u)
      __builtin_amdgcn_s_sleep(1);
    __builtin_amdgcn_fence(__ATOMIC_ACQUIRE, "agent");
  }
  __syncthreads();

  // ============ recurrence: 64 steps x {layer1, layer2} ============
  for (int u = 0; u < 64; ++u) {
    // ---------------- phase 1: layer 1 (no polls) ----------------
    short8 ah[16];
    // fresh operand issued FIRST; fully hidden under the x-GEMM below
    ldg16nw_sc0(ah, h1r + (size_t)((u + 1) & 1) * HSL + (size_t)xrow * 512 + quad * 8);
    f32x4 a1r = {}, a1z = {}, a1i = {}, a1h = {};
    {
      // x-GEMM: compiler scalar loads (R0-proven; measured non-bottleneck)
      // + streamed Wih1 nt loads (compiler-scheduled waits).
      const int c = u & 1;
      const u16* xc = c ? x1 : x0;
      const u32* pa = (const u32*)(xc + (size_t)xrow * 576 + (u - c) + quad * 8);
      #pragma unroll
      for (int hh = 0; hh < 2; ++hh) {
        u32 av[32];
        #pragma unroll
        for (int s = 0; s < 8; ++s)
          #pragma unroll
          for (int j = 0; j < 4; ++j) av[s * 4 + j] = pa[(hh * 8 + s) * 16 + j];
        short8 bx[24];
        #pragma unroll
        for (int s = 0; s < 8; ++s) {
          int ss = hh * 8 + s;
          bx[s]      = __builtin_nontemporal_load(&wfm1[(ss)      * 64 + lane]);
          bx[8 + s]  = __builtin_nontemporal_load(&wfm1[(16 + ss) * 64 + lane]);
          bx[16 + s] = __builtin_nontemporal_load(&wfm1[(32 + ss) * 64 + lane]);
        }
        #pragma unroll
        for (int s = 0; s < 8; ++s) {
          union { short8 v; u32 u4[4]; } a;
          #pragma unroll
          for (int j = 0; j < 4; ++j) a.u4[j] = av[s * 4 + j];
          a1r = MFMA(a.v, bx[s],      a1r, 0, 0, 0);
          a1z = MFMA(a.v, bx[8 + s],  a1z, 0, 0, 0);
          a1i = MFMA(a.v, bx[16 + s], a1i, 0, 0, 0);
        }
      }
    }
    VMCNT(0);                                  // ah ready (zero exposure)
    MFMA3X16_LDS(ah, 0, a1r, a1z, a1h);        // Whh1 from LDS
    {
      u32* hw = (u32*)(h1r + (size_t)(u & 1) * HSL);
      #pragma unroll
      for (int q = 0; q < 4; ++q) {
        float rg = sigm(a1r[q] + b1r);
        float zg = sigm(a1z[q] + b1z);
        float ng = tanh_fast(a1i[q] + b1i + rg * (a1h[q] + b1h));
        float hv = (1.0f - zg) * ng + zg * hreg1[q];
        hreg1[q] = hv;
        int row = R0 + w * 16 + quad * 4 + q;
        u16 b = f2bf(hv);
        int pb = __shfl_xor((int)(u32)b, 1);
        if (!(m16 & 1))
          hw[(row * 512 + nn) >> 1] = (u32)b | ((u32)(u16)pb << 16);
      }
    }
    asm volatile("s_waitcnt vmcnt(0)" ::: "memory");   // ring in L2
    __syncthreads();
    if (tid == 0)
      __hip_atomic_fetch_add(cA, 1u, __ATOMIC_RELAXED, __HIP_MEMORY_SCOPE_AGENT);

    // ---------------- phase 2: layer 2 ----------------
    waits_nf(cA, 32u * (unsigned)(u + 1), cB, 32u * (unsigned)u);
    short8 bb1[16], bb2[16];
    ldg16nw_sc0(bb1, h1r + (size_t)(u & 1) * HSL + (size_t)xrow * 512 + quad * 8);
    ldg16nw_sc0(bb2, h2r + (size_t)((u + 1) & 1) * HSL + (size_t)xrow * 512 + quad * 8);
    f32x4 a2r = {}, a2z = {}, a2i = {}, a2h = {};
    VMCNT(16);                                 // bb1 ready (asm-only window)
    MFMA3X16_LDS(bb1, 48, a2r, a2z, a2i);      // Wih2 from LDS
    VMCNT(0);                                  // bb2 ready (hidden by 48 MFMA)
    {
      // Whh2 streamed (nt loads, compiler-scheduled waits)
      #pragma unroll
      for (int hh = 0; hh < 2; ++hh) {
        short8 bx[24];
        #pragma unroll
        for (int s = 0; s < 8; ++s) {
          int ss = hh * 8 + s;
          bx[s]      = __builtin_nontemporal_load(&wfm2[(ss)      * 64 + lane]);
          bx[8 + s]  = __builtin_nontemporal_load(&wfm2[(16 + ss) * 64 + lane]);
          bx[16 + s] = __builtin_nontemporal_load(&wfm2[(32 + ss) * 64 + lane]);
        }
        #pragma unroll
        for (int s = 0; s < 8; ++s) {
          a2r = MFMA(bb2[hh * 8 + s], bx[s],      a2r, 0, 0, 0);
          a2z = MFMA(bb2[hh * 8 + s], bx[8 + s],  a2z, 0, 0, 0);
          a2h = MFMA(bb2[hh * 8 + s], bx[16 + s], a2h, 0, 0, 0);
        }
      }
    }
    float ya = 0.0f;
    if (wgi == 0 && u > 0) ya = ydot(bb2, wfcl, quad);   // y(u-1) from h2(u-1)
    {
      u32* hw = (u32*)(h2r + (size_t)(u & 1) * HSL);
      #pragma unroll
      for (int q = 0; q < 4; ++q) {
        float rg = sigm(a2r[q] + b2r);
        float zg = sigm(a2z[q] + b2z);
        float ng = tanh_fast(a2i[q] + b2i + rg * (a2h[q] + b2h));
        float hv = (1.0f - zg) * ng + zg * hreg2[q];
        hreg2[q] = hv;
        int row = R0 + w * 16 + quad * 4 + q;
        u16 b = f2bf(hv);
        int pb = __shfl_xor((int)(u32)b, 1);
        if (!(m16 & 1))
          hw[(row * 512 + nn) >> 1] = (u32)b | ((u32)(u16)pb << 16);
      }
    }
    asm volatile("s_waitcnt vmcnt(0)" ::: "memory");
    __syncthreads();
    if (tid == 0)
      __hip_atomic_fetch_add(cB, 1u, __ATOMIC_RELAXED, __HIP_MEMORY_SCOPE_AGENT);
    if (wgi == 0 && u > 0) {                   // y store: off critical path
      ya += __shfl_xor(ya, 16);
      ya += __shfl_xor(ya, 32);
      if (quad == 0) out[xrow * 64 + (u - 1)] = ya + bfcv;
    }
  }

  // final hidden states (fp32 exact)
  float* ho1 = out + 32768;
  float* ho2 = out + 32768 + 262144;
  #pragma unroll
  for (int q = 0; q < 4; ++q) {
    int row = R0 + w * 16 + quad * 4 + q;
    ho1[row * 512 + nn] = hreg1[q];
    ho2[row * 512 + nn] = hreg2[q];
  }
  // y(63) from the final h2 ring slot (63&1 = 1, local L2)
  if (wgi == 0) {
    waits_nf(cB, 32u * 64u, cB, 32u * 64u);
    short8 bz[16];
    ldg16nw_sc0(bz, h2r + (size_t)1 * HSL + (size_t)xrow * 512 + quad * 8);
    VMCNT(0);
    float ya = ydot(bz, wfcl, quad);
    ya += __shfl_xor(ya, 16);
    ya += __shfl_xor(ya, 32);
    if (quad == 0) out[xrow * 64 + 63] = ya + bfcv;
  }
}

extern "C" void kernel_launch(void* const* d_in, const int* in_sizes, int n_in,
                              void* d_out, int out_size, void* d_ws, size_t ws_size,
                              hipStream_t stream) {
  (void)in_sizes; (void)n_in; (void)out_size; (void)ws_size;
  hipMemsetAsync(d_out, 0, 32768 * sizeof(float), stream);   // y region
  hipMemsetAsync(d_ws, 0, 4096, stream);                     // counters
  unsigned* bar = (unsigned*)d_ws;
  u16* wsb = (u16*)((char*)d_ws + 4096);
  gru_fused<<<256, 256, 0, stream>>>(
      (const float*)d_in[0], (const float*)d_in[1], (const float*)d_in[2],
      (const float*)d_in[3], (const float*)d_in[4], (const float*)d_in[5], (const float*)d_in[6],
      (const float*)d_in[7], (const float*)d_in[8], (const float*)d_in[9], (const float*)d_in[10],
      (const float*)d_in[11], (const float*)d_in[12],
      (float*)d_out, wsb, bar);
}

// Round 10
// 1152.706 us; speedup vs baseline: 1.5282x; 1.5282x over previous
//
#include <hip/hip_runtime.h>
#include <hip/hip_bf16.h>
#include <math.h>

typedef __attribute__((ext_vector_type(8))) short short8;
typedef __attribute__((ext_vector_type(4))) float f32x4;
typedef unsigned short u16;
typedef unsigned int u32;

__device__ __forceinline__ u16 f2bf(float f) {
  union { float f; u32 u; } x; x.f = f;
  return (u16)((x.u + 0x7fffu + ((x.u >> 16) & 1u)) >> 16);
}
__device__ __forceinline__ float sigm(float v) {
  return __builtin_amdgcn_rcpf(1.0f + __expf(-v));
}
__device__ __forceinline__ float tanh_fast(float v) {
  return 1.0f - 2.0f * __builtin_amdgcn_rcpf(1.0f + __expf(2.0f * v));
}

#define MFMA __builtin_amdgcn_mfma_f32_16x16x32_bf16
#define XS  (512*576)   // one x copy (u16 elems)
#define HSL (512*512)   // one h ring slot (u16 elems)

// PROVEN: 16 x 16B loads (64B stride = one K-slice of a 512-col bf16 row).
#define LDG16_BODY(FL)                                        \
    "global_load_dwordx4 %0, %16, off " FL "\n\t"             \
    "global_load_dwordx4 %1, %16, off offset:64 " FL "\n\t"   \
    "global_load_dwordx4 %2, %16, off offset:128 " FL "\n\t"  \
    "global_load_dwordx4 %3, %16, off offset:192 " FL "\n\t"  \
    "global_load_dwordx4 %4, %16, off offset:256 " FL "\n\t"  \
    "global_load_dwordx4 %5, %16, off offset:320 " FL "\n\t"  \
    "global_load_dwordx4 %6, %16, off offset:384 " FL "\n\t"  \
    "global_load_dwordx4 %7, %16, off offset:448 " FL "\n\t"  \
    "global_load_dwordx4 %8, %16, off offset:512 " FL "\n\t"  \
    "global_load_dwordx4 %9, %16, off offset:576 " FL "\n\t"  \
    "global_load_dwordx4 %10, %16, off offset:640 " FL "\n\t" \
    "global_load_dwordx4 %11, %16, off offset:704 " FL "\n\t" \
    "global_load_dwordx4 %12, %16, off offset:768 " FL "\n\t" \
    "global_load_dwordx4 %13, %16, off offset:832 " FL "\n\t" \
    "global_load_dwordx4 %14, %16, off offset:896 " FL "\n\t" \
    "global_load_dwordx4 %15, %16, off offset:960 " FL
#define LDG16_OPS(a, base)                                                     \
    : "=&v"(a[0]), "=&v"(a[1]), "=&v"(a[2]), "=&v"(a[3]), "=&v"(a[4]),         \
      "=&v"(a[5]), "=&v"(a[6]), "=&v"(a[7]), "=&v"(a[8]), "=&v"(a[9]),         \
      "=&v"(a[10]), "=&v"(a[11]), "=&v"(a[12]), "=&v"(a[13]), "=&v"(a[14]),    \
      "=&v"(a[15])                                                             \
    : "v"(base) : "memory"

__device__ __forceinline__ void ldg16nw_sc0(short8 a[16], const u16* base) {
  asm volatile(LDG16_BODY("sc0") LDG16_OPS(a, base));    // local-L2 fresh
}

// Counted waits + sched_barrier (rule #18). Used ONLY in asm-only windows.
#define VMCNT(N) do { asm volatile("s_waitcnt vmcnt(" #N ")" ::: "memory"); \
                      __builtin_amdgcn_sched_barrier(0); } while (0)

// PROVEN (R0) rendezvous: poll two agent-scope atomic counters, then barrier.
__device__ __forceinline__ void waits_nf(unsigned* a, unsigned ta, unsigned* b, unsigned tb) {
  if (threadIdx.x == 0) {
    while (__hip_atomic_load(a, __ATOMIC_RELAXED, __HIP_MEMORY_SCOPE_AGENT) < ta)
      __builtin_amdgcn_s_sleep(1);
    while (__hip_atomic_load(b, __ATOMIC_RELAXED, __HIP_MEMORY_SCOPE_AGENT) < tb)
      __builtin_amdgcn_s_sleep(1);
  }
  __syncthreads();
}

// PROVEN (R5) per-lane 128-col dot vs LDS-resident W_fc.
__device__ __forceinline__ float ydot(const short8 a[16], const float* wfcl, int quad) {
  float y = 0.0f;
  #pragma unroll
  for (int s = 0; s < 16; ++s) {
    const float4 wa = *(const float4*)&wfcl[32 * s + quad * 8];
    const float4 wb = *(const float4*)&wfcl[32 * s + quad * 8 + 4];
    union { short8 v; u32 u4[4]; } aa; aa.v = a[s];
    #pragma unroll
    for (int k = 0; k < 4; ++k) {
      union { u32 u; float f; } lo, hi;
      lo.u = aa.u4[k] << 16;
      hi.u = aa.u4[k] & 0xffff0000u;
      float w0 = (k < 2) ? ((k & 1) ? wa.z : wa.x) : ((k & 1) ? wb.z : wb.x);
      float w1 = (k < 2) ? ((k & 1) ? wa.w : wa.y) : ((k & 1) ? wb.w : wb.y);
      y = fmaf(lo.f, w0, y);
      y = fmaf(hi.f, w1, y);
    }
  }
  return y;
}

// 16 K-slices x 3 gates from LDS (base block B0; gate stride 16 blocks).
#define MFMA3X16_LDS(A, B0, A0, A1, A2) do {                          \
    _Pragma("unroll")                                                 \
    for (int s_ = 0; s_ < 16; ++s_) {                                 \
      A0 = MFMA((A)[s_], wlds[((B0)+s_)*64+lane],    A0, 0, 0, 0);    \
      A1 = MFMA((A)[s_], wlds[((B0)+16+s_)*64+lane], A1, 0, 0, 0);    \
      A2 = MFMA((A)[s_], wlds[((B0)+32+s_)*64+lane], A2, 0, 0, 0); } } while (0)

// FUSED persistent 2-layer GRU — XCD-local steady state, zero MALL data.
// Identical to R9 (passed correctness) EXCEPT: weight-pack streams use plain
// CACHED loads instead of __builtin_nontemporal_load. R9's nt policy
// bypassed/evicted L2 -> 792MB HBM FETCH/dispatch = the whole 1.73ms runtime.
// Packs are static after init and L2-resident per XCD (written by the XCD's
// own WGs; one-time release fence at worst writes them back to MALL, giving
// a one-time ~3MB/XCD refill) -> steady-state pack reads are local L2 hits.
// Topology recap: 256 WGs = 8 groups (g = bid&7) x 32 col-blocks; group g
// owns rows 64g..64g+63 of BOTH layers; phase1 = layer1, phase2 = layer2.
// Rings: plain stores -> local-L2 dirty; sc0 asm reads. Sync: agent-atomic
// counters cA/cB. phase2(u) waits cA>=32(u+1), cB>=32u; phase1 never polls.
// LDS 96KB: Whh1 (0..47) + Wih2 (48..95). Workspace 6.43MB.
__global__ __launch_bounds__(256, 1) void gru_fused(
    const float* __restrict__ xin, const float* __restrict__ h1in, const float* __restrict__ h2in,
    const float* __restrict__ Wih1, const float* __restrict__ Whh1,
    const float* __restrict__ bih1, const float* __restrict__ bhh1,
    const float* __restrict__ Wih2, const float* __restrict__ Whh2,
    const float* __restrict__ bih2, const float* __restrict__ bhh2,
    const float* __restrict__ Wfc, const float* __restrict__ bfc,
    float* __restrict__ out, u16* __restrict__ wsb, unsigned* __restrict__ barc)
{
  const int bid  = blockIdx.x;
  const int g    = bid & 7;
  const int wgi  = bid >> 3;
  const int n0   = wgi * 16;
  const int tid  = threadIdx.x;
  const int w    = tid >> 6;
  const int lane = tid & 63;
  const int quad = lane >> 4;
  const int m16  = lane & 15;
  const int R0   = g * 64;
  const int xrow = R0 + w * 16 + m16;
  const int nn   = n0 + m16;

  u16* x0  = wsb;                     // [512][576] bf16
  u16* x1  = x0 + XS;                 // shifted copy (odd steps)
  u16* h1r = x1 + XS;                 // 2-slot ring
  u16* h2r = h1r + 2 * HSL;           // 2-slot ring
  short8* wfx  = (short8*)(h2r + 2 * HSL);              // packs
  short8* wfm1 = wfx + (size_t)wgi * 96 * 64;           // Wih1 blk 0..47
  short8* wfm2 = wfm1 + 48 * 64;                        // Whh2 blk 0..47

  __shared__ short8 wlds[96 * 64];    // Whh1 (0..47), Wih2 (48..95)
  __shared__ float wfcl[512];

  unsigned* cA = barc + g * 32;            // layer-1 step counter (group g)
  unsigned* cB = barc + 256 + g * 32;      // layer-2 step counter
  unsigned* cinit = barc + 512;

  // ---------------- one-time init (group-local writes) ----------------
  for (int i = wgi * 256 + tid; i < 64 * 575; i += 32 * 256) {
    int r = i / 575, c = i - r * 575;
    int row = R0 + r;
    u16 bv = f2bf(xin[row * 575 + c]);
    x0[row * 576 + c] = bv;
    if (c >= 1) x1[row * 576 + (c - 1)] = bv;
  }
  for (int i = tid; i < 64 * 16; i += 256) {      // ring slot 1 = h(-1)
    int r = i >> 4, cL = i & 15;
    int row = R0 + r, col = n0 + cL;
    h1r[HSL + row * 512 + col] = f2bf(h1in[row * 512 + col]);
    h2r[HSL + row * 512 + col] = f2bf(h2in[row * 512 + col]);
  }
  // packs: Wih1 (blk<48), Whh2 (blk>=48); per-wgi content, written
  // identically by all 8 groups (benign) -> L2-dirty copy on every XCD.
  for (int i = tid; i < 96 * 64; i += 256) {
    int blk = i >> 6, l = i & 63;
    int b = (blk < 48) ? blk : blk - 48;
    const float* M = blk < 48 ? Wih1 : Whh2;
    int t = b >> 4, s = b & 15;
    int gr = t * 512 + n0 + (l & 15);
    int k0 = s * 32 + (l >> 4) * 8;
    short8 pk;
    #pragma unroll
    for (int j = 0; j < 8; ++j) pk[j] = (short)f2bf(M[gr * 512 + k0 + j]);
    wfm1[blk * 64 + l] = pk;
  }
  // LDS: Whh1 (0..47), Wih2 (48..95)
  for (int i = tid; i < 96 * 64; i += 256) {
    int blk = i >> 6, l = i & 63;
    int b = (blk < 48) ? blk : blk - 48;
    const float* M = blk < 48 ? Whh1 : Wih2;
    int t = b >> 4, s = b & 15;
    int gr = t * 512 + n0 + (l & 15);
    int k0 = s * 32 + (l >> 4) * 8;
    short8 pk;
    #pragma unroll
    for (int j = 0; j < 8; ++j) pk[j] = (short)f2bf(M[gr * 512 + k0 + j]);
    wlds[blk * 64 + l] = pk;
  }
  for (int i = tid; i < 512; i += 256) wfcl[i] = Wfc[i];

  float hreg1[4], hreg2[4];
  #pragma unroll
  for (int q = 0; q < 4; ++q) {
    int row = R0 + w * 16 + quad * 4 + q;
    hreg1[q] = h1in[row * 512 + nn];
    hreg2[q] = h2in[row * 512 + nn];
  }

  const float b1r = bih1[nn] + bhh1[nn];
  const float b1z = bih1[512 + nn] + bhh1[512 + nn];
  const float b1i = bih1[1024 + nn];
  const float b1h = bhh1[1024 + nn];
  const float b2r = bih2[nn] + bhh2[nn];
  const float b2z = bih2[512 + nn] + bhh2[512 + nn];
  const float b2i = bih2[1024 + nn];
  const float b2h = bhh2[1024 + nn];
  const float bfcv = bfc[0];

  // PROVEN global init barrier: release (wb) + acquire (inv), one-time.
  __syncthreads();
  if (tid == 0) {
    __builtin_amdgcn_fence(__ATOMIC_RELEASE, "agent");
    __hip_atomic_fetch_add(cinit, 1u, __ATOMIC_RELAXED, __HIP_MEMORY_SCOPE_AGENT);
    while (__hip_atomic_load(cinit, __ATOMIC_RELAXED, __HIP_MEMORY_SCOPE_AGENT) < 256u)
      __builtin_amdgcn_s_sleep(1);
    __builtin_amdgcn_fence(__ATOMIC_ACQUIRE, "agent");
  }
  __syncthreads();

  // ============ recurrence: 64 steps x {layer1, layer2} ============
  for (int u = 0; u < 64; ++u) {
    // ---------------- phase 1: layer 1 (no polls) ----------------
    short8 ah[16];
    // fresh operand issued FIRST; fully hidden under the x-GEMM below
    ldg16nw_sc0(ah, h1r + (size_t)((u + 1) & 1) * HSL + (size_t)xrow * 512 + quad * 8);
    f32x4 a1r = {}, a1z = {}, a1i = {}, a1h = {};
    {
      // x-GEMM: compiler cached loads; Wih1 frags CACHED (L2-resident packs)
      const int c = u & 1;
      const u16* xc = c ? x1 : x0;
      const u32* pa = (const u32*)(xc + (size_t)xrow * 576 + (u - c) + quad * 8);
      #pragma unroll
      for (int hh = 0; hh < 2; ++hh) {
        u32 av[32];
        #pragma unroll
        for (int s = 0; s < 8; ++s)
          #pragma unroll
          for (int j = 0; j < 4; ++j) av[s * 4 + j] = pa[(hh * 8 + s) * 16 + j];
        short8 bx[24];
        #pragma unroll
        for (int s = 0; s < 8; ++s) {
          int ss = hh * 8 + s;
          bx[s]      = wfm1[(ss)      * 64 + lane];
          bx[8 + s]  = wfm1[(16 + ss) * 64 + lane];
          bx[16 + s] = wfm1[(32 + ss) * 64 + lane];
        }
        #pragma unroll
        for (int s = 0; s < 8; ++s) {
          union { short8 v; u32 u4[4]; } a;
          #pragma unroll
          for (int j = 0; j < 4; ++j) a.u4[j] = av[s * 4 + j];
          a1r = MFMA(a.v, bx[s],      a1r, 0, 0, 0);
          a1z = MFMA(a.v, bx[8 + s],  a1z, 0, 0, 0);
          a1i = MFMA(a.v, bx[16 + s], a1i, 0, 0, 0);
        }
      }
    }
    VMCNT(0);                                  // ah ready (zero exposure)
    MFMA3X16_LDS(ah, 0, a1r, a1z, a1h);        // Whh1 from LDS
    {
      u32* hw = (u32*)(h1r + (size_t)(u & 1) * HSL);
      #pragma unroll
      for (int q = 0; q < 4; ++q) {
        float rg = sigm(a1r[q] + b1r);
        float zg = sigm(a1z[q] + b1z);
        float ng = tanh_fast(a1i[q] + b1i + rg * (a1h[q] + b1h));
        float hv = (1.0f - zg) * ng + zg * hreg1[q];
        hreg1[q] = hv;
        int row = R0 + w * 16 + quad * 4 + q;
        u16 b = f2bf(hv);
        int pb = __shfl_xor((int)(u32)b, 1);
        if (!(m16 & 1))
          hw[(row * 512 + nn) >> 1] = (u32)b | ((u32)(u16)pb << 16);
      }
    }
    asm volatile("s_waitcnt vmcnt(0)" ::: "memory");   // ring in L2
    __syncthreads();
    if (tid == 0)
      __hip_atomic_fetch_add(cA, 1u, __ATOMIC_RELAXED, __HIP_MEMORY_SCOPE_AGENT);

    // ---------------- phase 2: layer 2 ----------------
    waits_nf(cA, 32u * (unsigned)(u + 1), cB, 32u * (unsigned)u);
    short8 bb1[16], bb2[16];
    ldg16nw_sc0(bb1, h1r + (size_t)(u & 1) * HSL + (size_t)xrow * 512 + quad * 8);
    ldg16nw_sc0(bb2, h2r + (size_t)((u + 1) & 1) * HSL + (size_t)xrow * 512 + quad * 8);
    f32x4 a2r = {}, a2z = {}, a2i = {}, a2h = {};
    VMCNT(16);                                 // bb1 ready (asm-only window)
    MFMA3X16_LDS(bb1, 48, a2r, a2z, a2i);      // Wih2 from LDS
    VMCNT(0);                                  // bb2 ready (hidden by 48 MFMA)
    {
      // Whh2 streamed via CACHED loads (L2-resident pack)
      #pragma unroll
      for (int hh = 0; hh < 2; ++hh) {
        short8 bx[24];
        #pragma unroll
        for (int s = 0; s < 8; ++s) {
          int ss = hh * 8 + s;
          bx[s]      = wfm2[(ss)      * 64 + lane];
          bx[8 + s]  = wfm2[(16 + ss) * 64 + lane];
          bx[16 + s] = wfm2[(32 + ss) * 64 + lane];
        }
        #pragma unroll
        for (int s = 0; s < 8; ++s) {
          a2r = MFMA(bb2[hh * 8 + s], bx[s],      a2r, 0, 0, 0);
          a2z = MFMA(bb2[hh * 8 + s], bx[8 + s],  a2z, 0, 0, 0);
          a2h = MFMA(bb2[hh * 8 + s], bx[16 + s], a2h, 0, 0, 0);
        }
      }
    }
    float ya = 0.0f;
    if (wgi == 0 && u > 0) ya = ydot(bb2, wfcl, quad);   // y(u-1) from h2(u-1)
    {
      u32* hw = (u32*)(h2r + (size_t)(u & 1) * HSL);
      #pragma unroll
      for (int q = 0; q < 4; ++q) {
        float rg = sigm(a2r[q] + b2r);
        float zg = sigm(a2z[q] + b2z);
        float ng = tanh_fast(a2i[q] + b2i + rg * (a2h[q] + b2h));
        float hv = (1.0f - zg) * ng + zg * hreg2[q];
        hreg2[q] = hv;
        int row = R0 + w * 16 + quad * 4 + q;
        u16 b = f2bf(hv);
        int pb = __shfl_xor((int)(u32)b, 1);
        if (!(m16 & 1))
          hw[(row * 512 + nn) >> 1] = (u32)b | ((u32)(u16)pb << 16);
      }
    }
    asm volatile("s_waitcnt vmcnt(0)" ::: "memory");
    __syncthreads();
    if (tid == 0)
      __hip_atomic_fetch_add(cB, 1u, __ATOMIC_RELAXED, __HIP_MEMORY_SCOPE_AGENT);
    if (wgi == 0 && u > 0) {                   // y store: off critical path
      ya += __shfl_xor(ya, 16);
      ya += __shfl_xor(ya, 32);
      if (quad == 0) out[xrow * 64 + (u - 1)] = ya + bfcv;
    }
  }

  // final hidden states (fp32 exact)
  float* ho1 = out + 32768;
  float* ho2 = out + 32768 + 262144;
  #pragma unroll
  for (int q = 0; q < 4; ++q) {
    int row = R0 + w * 16 + quad * 4 + q;
    ho1[row * 512 + nn] = hreg1[q];
    ho2[row * 512 + nn] = hreg2[q];
  }
  // y(63) from the final h2 ring slot (63&1 = 1, local L2)
  if (wgi == 0) {
    waits_nf(cB, 32u * 64u, cB, 32u * 64u);
    short8 bz[16];
    ldg16nw_sc0(bz, h2r + (size_t)1 * HSL + (size_t)xrow * 512 + quad * 8);
    VMCNT(0);
    float ya = ydot(bz, wfcl, quad);
    ya += __shfl_xor(ya, 16);
    ya += __shfl_xor(ya, 32);
    if (quad == 0) out[xrow * 64 + 63] = ya + bfcv;
  }
}

extern "C" void kernel_launch(void* const* d_in, const int* in_sizes, int n_in,
                              void* d_out, int out_size, void* d_ws, size_t ws_size,
                              hipStream_t stream) {
  (void)in_sizes; (void)n_in; (void)out_size; (void)ws_size;
  hipMemsetAsync(d_out, 0, 32768 * sizeof(float), stream);   // y region
  hipMemsetAsync(d_ws, 0, 4096, stream);                     // counters
  unsigned* bar = (unsigned*)d_ws;
  u16* wsb = (u16*)((char*)d_ws + 4096);
  gru_fused<<<256, 256, 0, stream>>>(
      (const float*)d_in[0], (const float*)d_in[1], (const float*)d_in[2],
      (const float*)d_in[3], (const float*)d_in[4], (const float*)d_in[5], (const float*)d_in[6],
      (const float*)d_in[7], (const float*)d_in[8], (const float*)d_in[9], (const float*)d_in[10],
      (const float*)d_in[11], (const float*)d_in[12],
      (float*)d_out, wsb, bar);
}